// Round 10
// baseline (314.831 us; speedup 1.0000x reference)
//
#include <hip/hip_runtime.h>
#include <cstdint>
#include <cstddef>

// ---------------- common ----------------
typedef __attribute__((ext_vector_type(8))) short short8;   // 8 x bf16 (4 VGPR)
typedef __attribute__((ext_vector_type(4))) short short4_;  // 4 x bf16 (2 VGPR)
typedef __attribute__((ext_vector_type(4))) float f32x4;    // MFMA C/D 16x16
typedef __attribute__((ext_vector_type(4))) unsigned int uint4_;

__device__ inline unsigned short bf16rne(float f) {
    uint32_t u = __builtin_bit_cast(uint32_t, f);
    u += 0x7fffu + ((u >> 16) & 1u);
    return (unsigned short)(u >> 16);
}

// async global->LDS, 16 B per lane. LDS dest = wave-uniform base + lane*16.
#define GLDS(g, l)                                                              \
    __builtin_amdgcn_global_load_lds(                                           \
        (const __attribute__((address_space(1))) void*)(g),                     \
        (__attribute__((address_space(3))) void*)(l), 16, 0, 0)

// ---------------- fp32 -> bf16 convert ----------------
__global__ void cvt_kernel(const float* __restrict__ src,
                           unsigned short* __restrict__ dst, int n8) {
    int i = blockIdx.x * blockDim.x + threadIdx.x;
    if (i >= n8) return;
    const float4* s = (const float4*)src + (size_t)i * 2;
    float4 a = s[0], b = s[1];
    uint32_t w0 = bf16rne(a.x) | ((uint32_t)bf16rne(a.y) << 16);
    uint32_t w1 = bf16rne(a.z) | ((uint32_t)bf16rne(a.w) << 16);
    uint32_t w2 = bf16rne(b.x) | ((uint32_t)bf16rne(b.y) << 16);
    uint32_t w3 = bf16rne(b.z) | ((uint32_t)bf16rne(b.w) << 16);
    uint4 o; o.x = w0; o.y = w1; o.z = w2; o.w = w3;
    ((uint4*)dst)[i] = o;
}

// ---------------- QKV projection GEMM (unchanged, R6-passing) ----------------
// 256x256 tile, BK=64, 8 waves, 128 KB LDS dbuf, counted vmcnt(8), XOR chunk
// swizzle both-sides, XCD slab decode. Outputs: q d-major pre-scaled 0.125,
// k row-major, v d-major.
__global__ __launch_bounds__(512, 2) void qkv_gemm(
    const unsigned short* __restrict__ X, const unsigned short* __restrict__ W,
    const float* __restrict__ bqkv,
    unsigned short* __restrict__ qo, unsigned short* __restrict__ ko,
    unsigned short* __restrict__ vo)
{
    __shared__ unsigned short smem[65536];   // 128 KB: As[2][16384] | Bs[2][16384]
    unsigned short* As = smem;
    unsigned short* Bs = smem + 32768;

    const int tid  = threadIdx.x;
    const int f    = blockIdx.x;
    const int per  = gridDim.x >> 3;          // grid % 8 == 0
    const int wk   = (f & 7) * per + (f >> 3);
    const int m0   = (wk / 9) * 256;
    const int n0   = (wk % 9) * 256;
    const int wid  = tid >> 6;
    const int lane = tid & 63;
    const int m16  = lane & 15;
    const int quad = lane >> 4;
    const int wm   = wid >> 2;                // 0..1 : 128 rows each
    const int wn   = wid & 3;                 // 0..3 : 64 cols each (= one head)

    f32x4 acc[8][4];
    #pragma unroll
    for (int i = 0; i < 8; i++)
        #pragma unroll
        for (int j = 0; j < 4; j++) acc[i][j] = (f32x4){0.f, 0.f, 0.f, 0.f};

    auto stage = [&](int buf, int k0) {
        #pragma unroll
        for (int rd = 0; rd < 4; ++rd) {
            int id = rd * 512 + tid;              // 0..2047 : 256 rows x 8 chunks
            int row = id >> 3;
            int cs = (id & 7) ^ (row & 7);
            GLDS(X + (size_t)(m0 + row) * 768 + k0 + cs * 8,
                 &As[buf * 16384 + id * 8]);
        }
        #pragma unroll
        for (int rd = 0; rd < 4; ++rd) {
            int id = rd * 512 + tid;
            int row = id >> 3;
            int cs = (id & 7) ^ (row & 7);
            GLDS(W + (size_t)(n0 + row) * 768 + k0 + cs * 8,
                 &Bs[buf * 16384 + id * 8]);
        }
    };

    stage(0, 0);
    stage(1, 64);

    const int arow0 = wm * 128 + m16;
    const int brow0 = wn * 64 + m16;
    const int swz   = m16 & 7;

    for (int t = 0; t < 12; ++t) {
        const int cur = t & 1;
        if (t == 11) asm volatile("s_waitcnt vmcnt(0)" ::: "memory");
        else         asm volatile("s_waitcnt vmcnt(8)" ::: "memory");
        __builtin_amdgcn_s_barrier();

        __builtin_amdgcn_s_setprio(1);
        #pragma unroll
        for (int ks = 0; ks < 2; ++ks) {
            const int ch = ((ks * 4 + quad) ^ swz) * 8;
            short8 b[4];
            #pragma unroll
            for (int nb = 0; nb < 4; nb++)
                b[nb] = *(const short8*)&Bs[cur * 16384 + (brow0 + nb * 16) * 64 + ch];
            #pragma unroll
            for (int mb = 0; mb < 8; mb++) {
                short8 a = *(const short8*)&As[cur * 16384 + (arow0 + mb * 16) * 64 + ch];
                #pragma unroll
                for (int nb = 0; nb < 4; nb++)
                    acc[mb][nb] = __builtin_amdgcn_mfma_f32_16x16x32_bf16(
                        a, b[nb], acc[mb][nb], 0, 0, 0);
            }
        }
        __builtin_amdgcn_s_setprio(0);

        __builtin_amdgcn_s_barrier();
        asm volatile("" ::: "memory");
        if (t < 10) stage(cur, (t + 2) * 64);
    }

    float bias_n[4];
    #pragma unroll
    for (int nb = 0; nb < 4; nb++) bias_n[nb] = bqkv[n0 + wn * 64 + nb * 16 + m16];

    const int which = n0 / 768;
    const int hbase = (n0 % 768) >> 6;
    const int bI  = m0 >> 10;
    const int ns0 = m0 & 1023;

    if (which != 1) {
        unsigned short* outp = (which == 0) ? qo : vo;
        const float scl = (which == 0) ? 0.125f : 1.0f;
        const int h = hbase + wn;
        #pragma unroll
        for (int mb = 0; mb < 8; ++mb)
            #pragma unroll
            for (int nb = 0; nb < 4; ++nb) {
                int d   = nb * 16 + m16;
                int pos = ns0 + wm * 128 + mb * 16 + quad * 4;
                short4_ v4;
                #pragma unroll
                for (int r = 0; r < 4; ++r)
                    v4[r] = (short)bf16rne((acc[mb][nb][r] + bias_n[nb]) * scl);
                *(short4_*)(outp + ((size_t)(bI * 12 + h) * 64 + d) * 1024 + pos) = v4;
            }
        return;
    }

    #pragma unroll
    for (int pass = 0; pass < 2; ++pass) {
        __syncthreads();
        if ((wn >> 1) == pass) {
            const int colb = (wn & 1) * 64;
            #pragma unroll
            for (int mb = 0; mb < 8; mb++)
                #pragma unroll
                for (int nb = 0; nb < 4; nb++)
                    #pragma unroll
                    for (int r = 0; r < 4; r++) {
                        float v = acc[mb][nb][r] + bias_n[nb];
                        smem[(wm * 128 + mb * 16 + quad * 4 + r) * 132 +
                             colb + nb * 16 + m16] = bf16rne(v);
                    }
        }
        __syncthreads();
        #pragma unroll
        for (int rd = 0; rd < 8; ++rd) {
            int id = rd * 512 + tid;
            int row = id >> 4, c = id & 15;
            short4_ lo = *(const short4_*)&smem[row * 132 + c * 8];
            short4_ hi = *(const short4_*)&smem[row * 132 + c * 8 + 4];
            short8 v8 = __builtin_shufflevector(lo, hi, 0, 1, 2, 3, 4, 5, 6, 7);
            int h  = hbase + pass * 2 + (c >> 3);
            int dc = (c & 7) * 8;
            unsigned short* dst =
                ko + ((size_t)(bI * 12 + h) * 1024 + ns0 + row) * 64 + dc;
            *(short8*)dst = v8;
        }
    }
}

// ---------------- flash attention (R15: R6 base + full-rate 16x16x32 PV) -----
// R7-R9 (32x32 path) burned: 2 container crashes + absmax 19 — unverified
// 32x32 A/B lane mappings implicated. This version = the R6-PASSING kernel
// with ONE change, using only session-verified layouts: PV switches from
// 16 x mfma_16x16x16bf16_1k (K=16, half-FLOP legacy shape) to
// 8 x mfma_f32_16x16x32_bf16 (full rate; A/B/C layouts proven by QK^T here).
// PV B-frag (P^T, col=m16, k=8*quad+j) built from the verified S C-layout
// (pos = cb*16 + quad*4 + r) by a fixed lane permutation:
//   value for (quad, j): pos = ks*32 + 8*quad + j -> holder lane
//   (m16, quad_src=(pos>>2)&3), reg cb=pos>>4, r=pos&3. Packed pairs
//   pk[cb][w] = (pos cb*16+4*quad+2w, +1). Routing: src0 = m16+32*(quad&1)
//   (j 0..3), src1 = src0+16 (j 4..7), reg cb = 2ks + (quad>>1).
//   Verified cases: (quad=1,ks=0,j=0) -> src0=m16+32 pk[0][0]=(8,9) ok;
//   (quad=3,ks=1,j=6) -> src1=m16+48(self) pk[3][1]=(62,63) ok.
//   8 __shfl + 4 selects per ks; B-frag shared across all 4 nb d-blocks.
// V A-frag: one b128 at slot (4*ks+quad)*64 + nb*16 + m16 (= V^T[d][pos
// 32ks+8quad..+8], same Vs layout family as the R6-passing b64 reads).
// Everything else byte-identical to R6: 512 thr, q-tile 128, 32 KB dbuf,
// (512,4), T3 prefetch, bias->sc C-init, exp2-fma, defer-rescale, setprio.
__global__ __launch_bounds__(512, 4) void attn_kernel(
    const unsigned short* __restrict__ Q, const unsigned short* __restrict__ K,
    const unsigned short* __restrict__ Vt, const float* __restrict__ bias,
    const float* __restrict__ dvec, float* __restrict__ out, int nbh8)
{
    __shared__ unsigned short Ks[2][4096];   // 2 x 512 slots * 8 elems = 16 KB
    __shared__ unsigned short Vs[2][4096];   // 2 x 512 slots * 8 elems = 16 KB

    const int tid  = threadIdx.x;
    const int wid  = tid >> 6;               // 0..7
    const int lane = tid & 63;
    const int m16  = lane & 15;
    const int quad = lane >> 4;

    const int f    = blockIdx.x;
    const int xcd  = f & 7;
    const int r_   = f >> 3;
    const int qt   = r_ & 7;                 // 8 q-tiles of 128 rows
    const int bhl  = r_ >> 3;
    const int bh   = xcd * nbh8 + bhl;
    const int b = bh / 12, h = bh % 12;
    const int q0 = qt * 128;
    const int qrow = q0 + wid * 16 + m16;    // this lane's q row (column of S^T)

    const unsigned short* Qb = Q  + (size_t)bh * 65536;
    const unsigned short* Kb = K  + (size_t)bh * 65536;
    const unsigned short* Vb = Vt + (size_t)bh * 65536;
    const float* brow = bias + (size_t)qrow * 1024 + quad * 4;

    // kv-invariant staging source offsets (hole-free, all 512 lanes active)
    int k_src, v_src;
    {
        int pos = tid >> 3, dbs = tid & 7;
        int db = dbs ^ (pos & 7);             // un-swizzle: slot id holds this db
        k_src = pos * 64 + db * 8;
        int pb = tid >> 6, d = tid & 63;
        v_src = d * 1024 + pb * 8;
    }

    // Q fragments from d-major Q: lane (m16,quad) needs dims quad*8..+8 (qf0)
    // and 32+quad*8..+8 (qf1) of row qrow -> 16 scalar loads, once per block.
    short8 qf0, qf1;
    #pragma unroll
    for (int j = 0; j < 8; ++j) {
        qf0[j] = (short)Qb[(size_t)(quad * 8 + j) * 1024 + qrow];
        qf1[j] = (short)Qb[(size_t)(32 + quad * 8 + j) * 1024 + qrow];
    }

    f32x4 acc[4];
    #pragma unroll
    for (int nb = 0; nb < 4; nb++) acc[nb] = (f32x4){0.f, 0.f, 0.f, 0.f};
    float m_i = -3.0e38f, l_i = 0.f;
    const float L2E = 1.4426950408889634f;

    // prologue: stage tile 0 + preload bias tile 0
    GLDS(Kb + k_src, &Ks[0][tid * 8]);
    GLDS(Vb + v_src, &Vs[0][tid * 8]);
    float4 bv[4];
    #pragma unroll
    for (int cb = 0; cb < 4; ++cb) bv[cb] = *(const float4*)(brow + cb * 16);
    __syncthreads();

    const int srcA = m16 + ((quad & 1) << 5);   // PV shfl source (j 0..3)
    const bool hi2 = (quad >> 1) != 0;          // reg-select: cb = 2ks+(quad>>1)

    for (int kv = 0; kv < 16; ++kv) {
        const int cur = kv & 1;
        const int k0n = (kv + 1) * 64;

        // S^T C-init = bias (Q pre-scaled by 0.125 -> no scale ops needed).
        f32x4 sc[4];
        #pragma unroll
        for (int cb = 0; cb < 4; ++cb) {
            sc[cb][0] = bv[cb].x;
            sc[cb][1] = bv[cb].y;
            sc[cb][2] = bv[cb].z;
            sc[cb][3] = bv[cb].w;
        }

        // prefetch tile kv+1 (lands during this iter's compute; barrier drains)
        if (kv < 15) {
            GLDS(Kb + (size_t)k0n * 64 + k_src, &Ks[cur ^ 1][tid * 8]);
            GLDS(Vb + (size_t)k0n + v_src, &Vs[cur ^ 1][tid * 8]);
            #pragma unroll
            for (int cb = 0; cb < 4; ++cb)
                bv[cb] = *(const float4*)(brow + k0n + cb * 16);
        }

        // S^T = bias + K·Q'^T : sc[cb] rows = pos cb*16+quad*4+r, col = qrow
        __builtin_amdgcn_s_setprio(1);
        #pragma unroll
        for (int ks = 0; ks < 2; ++ks) {
            #pragma unroll
            for (int cb = 0; cb < 4; ++cb) {
                int pos = cb * 16 + m16;
                int slot = pos * 8 + ((ks * 4 + quad) ^ (m16 & 7));
                short8 a = *(const short8*)&Ks[cur][slot * 8];
                sc[cb] = __builtin_amdgcn_mfma_f32_16x16x32_bf16(
                    a, (ks == 0) ? qf0 : qf1, sc[cb], 0, 0, 0);
            }
        }
        __builtin_amdgcn_s_setprio(0);

        // running max (sc already in final domain)
        float mx = -3.0e38f;
        #pragma unroll
        for (int cb = 0; cb < 4; ++cb)
            mx = fmaxf(mx, fmaxf(fmaxf(sc[cb][0], sc[cb][1]), fmaxf(sc[cb][2], sc[cb][3])));
        mx = fmaxf(mx, __shfl_xor(mx, 16, 64));
        mx = fmaxf(mx, __shfl_xor(mx, 32, 64));

        // T13 defer-rescale (THR=0: exact)
        if (!__all(mx <= m_i)) {
            float mnew = fmaxf(m_i, mx);
            float al = __builtin_amdgcn_exp2f((m_i - mnew) * L2E);
            m_i = mnew;
            l_i *= al;
            #pragma unroll
            for (int nb = 0; nb < 4; nb++) {
                acc[nb][0] *= al; acc[nb][1] *= al;
                acc[nb][2] *= al; acc[nb][3] *= al;
            }
        }
        const float nmL = -m_i * L2E;

        // exp2(fma) + row-sum + pack P^T pairs: pk[cb][w] = (cb*16+4q+2w, +1)
        float rs = 0.f;
        unsigned int pk[4][2];
        #pragma unroll
        for (int cb = 0; cb < 4; ++cb) {
            float p0 = __builtin_amdgcn_exp2f(__builtin_fmaf(sc[cb][0], L2E, nmL));
            float p1 = __builtin_amdgcn_exp2f(__builtin_fmaf(sc[cb][1], L2E, nmL));
            float p2 = __builtin_amdgcn_exp2f(__builtin_fmaf(sc[cb][2], L2E, nmL));
            float p3 = __builtin_amdgcn_exp2f(__builtin_fmaf(sc[cb][3], L2E, nmL));
            rs += (p0 + p1) + (p2 + p3);
            pk[cb][0] = __builtin_amdgcn_perm(__builtin_bit_cast(uint32_t, p1),
                                              __builtin_bit_cast(uint32_t, p0), 0x07060302u);
            pk[cb][1] = __builtin_amdgcn_perm(__builtin_bit_cast(uint32_t, p3),
                                              __builtin_bit_cast(uint32_t, p2), 0x07060302u);
        }
        rs += __shfl_xor(rs, 16, 64);
        rs += __shfl_xor(rs, 32, 64);
        l_i += rs;

        // O^T += V^T · P^T — full-rate 16x16x32: B-frag via lane-permute of pk
        __builtin_amdgcn_s_setprio(1);
        #pragma unroll
        for (int ks = 0; ks < 2; ++ks) {
            unsigned int a0 = __shfl(pk[2 * ks][0],     srcA,      64);
            unsigned int a1 = __shfl(pk[2 * ks][1],     srcA,      64);
            unsigned int b0 = __shfl(pk[2 * ks + 1][0], srcA,      64);
            unsigned int b1 = __shfl(pk[2 * ks + 1][1], srcA,      64);
            unsigned int c0 = __shfl(pk[2 * ks][0],     srcA + 16, 64);
            unsigned int c1 = __shfl(pk[2 * ks][1],     srcA + 16, 64);
            unsigned int d0 = __shfl(pk[2 * ks + 1][0], srcA + 16, 64);
            unsigned int d1 = __shfl(pk[2 * ks + 1][1], srcA + 16, 64);
            uint4_ pd;
            pd[0] = hi2 ? b0 : a0;   // j 0,1 : pos ks*32+8q+{0,1}
            pd[1] = hi2 ? b1 : a1;   // j 2,3
            pd[2] = hi2 ? d0 : c0;   // j 4,5
            pd[3] = hi2 ? d1 : c1;   // j 6,7
            short8 pf8 = __builtin_bit_cast(short8, pd);
            #pragma unroll
            for (int nb = 0; nb < 4; ++nb) {
                int slot = (4 * ks + quad) * 64 + nb * 16 + m16;
                short8 av = *(const short8*)&Vs[cur][slot * 8];
                acc[nb] = __builtin_amdgcn_mfma_f32_16x16x32_bf16(
                    av, pf8, acc[nb], 0, 0, 0);
            }
        }
        __builtin_amdgcn_s_setprio(0);

        // one barrier per iter: waits this iter's LDS reads AND drains the
        // prefetch (issued a full compute phase ago -> cheap)
        __syncthreads();
    }

    // epilogue: out = d[qrow]/l * O ; O^T C-layout: lane holds d = nb*16+quad*4+r
    float scl = dvec[qrow] / l_i;
    #pragma unroll
    for (int nb = 0; nb < 4; ++nb) {
        float4 o;
        o.x = acc[nb][0] * scl; o.y = acc[nb][1] * scl;
        o.z = acc[nb][2] * scl; o.w = acc[nb][3] * scl;
        *(float4*)(out + ((size_t)b * 1024 + qrow) * 768 + h * 64 + nb * 16 + quad * 4) = o;
    }
}

// ---------------- launch ----------------
extern "C" void kernel_launch(void* const* d_in, const int* in_sizes, int n_in,
                              void* d_out, int out_size, void* d_ws, size_t ws_size,
                              hipStream_t stream) {
    const float* x     = (const float*)d_in[0];   // (16,1024,768)
    const float* w     = (const float*)d_in[1];   // (2304,768)
    const float* bqkv  = (const float*)d_in[2];   // (2304,)
    const float* dvec  = (const float*)d_in[3];   // (1024,)
    const float* bbias = (const float*)d_in[4];   // (1024,1024)
    float* out = (float*)d_out;

    char* ws = (char*)d_ws;
    unsigned short* wb = (unsigned short*)ws;                        // 2304*768 bf16
    unsigned short* xb = (unsigned short*)((char*)d_out + 25165824); // 16*1024*768 bf16

    cvt_kernel<<<6144, 256, 0, stream>>>(x, xb, 1572864);            // all x -> bf16
    cvt_kernel<<<864, 256, 0, stream>>>(w, wb, 221184);              // w -> bf16

    const size_t NEED_FULL = 3538944ull + 3ull * 25165824ull;        // 79,036,416
    if (ws_size >= NEED_FULL) {
        unsigned short* qb = (unsigned short*)(ws + 3538944);        // Q^T d-major
        unsigned short* kb = qb + 12582912;
        unsigned short* vb = kb + 12582912;                          // V^T d-major
        qkv_gemm<<<576, 512, 0, stream>>>(xb, wb, bqkv, qb, kb, vb);
        attn_kernel<<<1536, 512, 0, stream>>>(qb, kb, vb, bbias, dvec, out, 24);
    } else {
        unsigned short* qb = (unsigned short*)(ws + 3538944);
        unsigned short* kb = qb + 3145728;
        unsigned short* vb = kb + 3145728;
        for (int c = 0; c < 4; ++c) {
            const unsigned short* xc = xb + (size_t)c * 3145728;     // 4 batches
            qkv_gemm<<<144, 512, 0, stream>>>(xc, wb, bqkv, qb, kb, vb);
            attn_kernel<<<384, 512, 0, stream>>>(
                qb, kb, vb, bbias, dvec, out + (size_t)c * 3145728, 6);
        }
    }
}